// Round 28
// baseline (120.331 us; speedup 1.0000x reference)
//
// r28: r27 + attn V direct-to-register (T14): V loads issued at loop top straight to VGPRs,
//      no LDS round-trip for V; K staging/rotation unchanged; merge region in dead K buffer.
#include <hip/hip_runtime.h>
#include <stdint.h>

typedef __attribute__((ext_vector_type(8))) short bf16x8;
typedef __attribute__((ext_vector_type(8))) unsigned short ushort8;
typedef __attribute__((ext_vector_type(4))) float f32x4;
typedef __attribute__((ext_vector_type(16))) float f32x16;

constexpr int DM = 1024;   // d_model
constexpr int SQ = 2048;   // seq len
constexpr int NB = 2;      // batch
constexpr int NH = 16;     // heads
constexpr int DK = 64;     // head dim
constexpr int M  = NB * SQ; // 4096 rows

__device__ inline float bf2f(unsigned short u) {
    union { uint32_t i; float f; } c; c.i = ((uint32_t)u) << 16; return c.f;
}
__device__ inline unsigned short f2bf(float f) {
    union { float f; uint32_t i; } c; c.f = f;
    uint32_t r = c.i + 0x7FFFu + ((c.i >> 16) & 1u);   // round-to-nearest-even
    return (unsigned short)(r >> 16);
}
__device__ inline float exp2v(float x) {    // v_exp_f32: D = 2^S0
    float r;
    asm("v_exp_f32 %0, %1" : "=v"(r) : "v"(x));
    return r;
}
__device__ inline uint32_t cvtpk(float lo, float hi) {
    uint32_t r;
    asm("v_cvt_pk_bf16_f32 %0, %1, %2" : "=v"(r) : "v"(lo), "v"(hi));
    return r;
}
__device__ inline uint32_t sx32(uint32_t v) {   // exchange with partner lane (l ^ 32)
    return (uint32_t)__shfl_xor((int)v, 32);
}
__device__ inline float sx32f(float v) {
    return __shfl_xor(v, 32);
}
__device__ inline bf16x8 mkfrag(uint32_t a, uint32_t b, uint32_t c, uint32_t d) {
    union { bf16x8 v; uint32_t u[4]; } m;
    m.u[0] = a; m.u[1] = b; m.u[2] = c; m.u[3] = d;
    return m.v;
}
__device__ inline void gload_lds16(const unsigned short* g, unsigned short* l) {
    __builtin_amdgcn_global_load_lds(
        (const __attribute__((address_space(1))) void*)g,
        (__attribute__((address_space(3))) void*)l, 16, 0, 0);
}

// ------- merged setup: x fp32->bf16 (bids 0..2047) + 4x W transpose-convert (bids 2048..6143) -------
__global__ __launch_bounds__(256) void cvt_all(const float* __restrict__ x,
                                               unsigned short* __restrict__ xb,
                                               const float* __restrict__ W0,
                                               const float* __restrict__ W1,
                                               const float* __restrict__ W2,
                                               const float* __restrict__ W3,
                                               unsigned short* __restrict__ WtBase) {
    __shared__ float tile[32][33];
    const int bid = blockIdx.x;
    const int t = threadIdx.x;
    if (bid < 2048) {   // --- cvt_x part ---
        int idx = (bid * 256 + t) * 8;
        const float* p = x + idx;
        ushort8 o;
#pragma unroll
        for (int i = 0; i < 8; ++i) o[i] = f2bf(p[i]);
        *(ushort8*)(xb + idx) = o;
        return;
    }
    // --- cvt_w part ---
    const int wid = bid - 2048;          // 0..4095
    const int z = wid >> 10;             // matrix 0..3
    const int rem = wid & 1023;
    const int bx = rem & 31, by = rem >> 5;
    const float* W = (z == 0) ? W0 : (z == 1) ? W1 : (z == 2) ? W2 : W3;
    unsigned short* Wt = WtBase + (size_t)z * DM * DM;
    const int tx = t & 31, ty = t >> 5;  // 32 x 8 (same mapping as the old (32,8) block)
#pragma unroll
    for (int j = 0; j < 4; ++j)
        tile[ty + j * 8][tx] = W[(size_t)(by * 32 + ty + j * 8) * DM + bx * 32 + tx];
    __syncthreads();
#pragma unroll
    for (int j = 0; j < 4; ++j)
        Wt[(size_t)(bx * 32 + ty + j * 8) * DM + by * 32 + tx] = f2bf(tile[tx][ty + j * 8]);
}

// ---------------- bf16 MFMA GEMM, 128x128 tile, BK=32 (QKV projection, r20) ----------------
// Fused QKV. Q written PRE-SCALED by 0.125*log2e; Q,K [B,H,S,DK]; V^T [B,H,DK,S].
__global__ __launch_bounds__(256) void gemm128(const unsigned short* __restrict__ A,
                                               const unsigned short* __restrict__ Bt,
                                               const float* __restrict__ b0,
                                               const float* __restrict__ b1,
                                               const float* __restrict__ b2,
                                               unsigned short* __restrict__ outp) {
    constexpr int K = 1024;
    __shared__ __align__(16) unsigned short As[128 * 32];
    __shared__ __align__(16) unsigned short Bs[128 * 32];
    const int t = threadIdx.x;
    const int w = t >> 6, l = t & 63;
    const int l15 = l & 15, lg = l >> 4;
    const int wr = w >> 1, wc = w & 1;
    const int bx = blockIdx.x, by = blockIdx.y;

    f32x4 acc[4][4] = {};

    const int srow = l >> 2;
    const int sk   = (l & 3) * 8;
    const unsigned short* Abase = A  + (size_t)(by * 128) * K;
    const unsigned short* Bbase = Bt + (size_t)(bx * 128) * K;

    for (int k0 = 0; k0 < K; k0 += 32) {
#pragma unroll
        for (int i = 0; i < 2; ++i) {
            const int row = w * 32 + i * 16 + srow;
            gload_lds16(Abase + (size_t)row * K + k0 + sk, &As[row * 32 + sk]);
            gload_lds16(Bbase + (size_t)row * K + k0 + sk, &Bs[row * 32 + sk]);
        }
        __syncthreads();

        bf16x8 af[4], bfr[4];
#pragma unroll
        for (int mi = 0; mi < 4; ++mi)
            af[mi] = *(const bf16x8*)&As[(wr * 64 + mi * 16 + l15) * 32 + lg * 8];
#pragma unroll
        for (int ni = 0; ni < 4; ++ni)
            bfr[ni] = *(const bf16x8*)&Bs[(wc * 64 + ni * 16 + l15) * 32 + lg * 8];
#pragma unroll
        for (int mi = 0; mi < 4; ++mi)
#pragma unroll
            for (int ni = 0; ni < 4; ++ni)
                acc[mi][ni] = __builtin_amdgcn_mfma_f32_16x16x32_bf16(af[mi], bfr[ni], acc[mi][ni], 0, 0, 0);
        __syncthreads();
    }

#pragma unroll
    for (int ni = 0; ni < 4; ++ni) {
        const int n = bx * 128 + wc * 64 + ni * 16 + l15;
        const int mat = n >> 10;   // wave-uniform (128-tile never spans matrices)
        const float* bp = (mat == 0) ? b0 : (mat == 1) ? b1 : b2;
        const float bias = bp[n & 1023];
#pragma unroll
        for (int mi = 0; mi < 4; ++mi)
#pragma unroll
            for (int i = 0; i < 4; ++i) {
                const int m = by * 128 + wr * 64 + mi * 16 + lg * 4 + i;
                float v = acc[mi][ni][i] + bias;
                const int c = n & 1023;
                if (mat == 0) v *= 0.18033688f;   // 0.125 * log2(e): scores in exp2 domain
                const int h = c >> 6, d = c & 63;
                const int b = m >> 11, si = m & 2047;
                size_t idx;
                if (mat == 2)   // V transposed: [B,H,DK,S]
                    idx = ((size_t)(b * NH + h) * DK + d) * SQ + si;
                else
                    idx = ((size_t)(b * NH + h) * SQ + si) * DK + d;
                outp[(size_t)mat * (NB * NH * SQ * DK) + idx] = f2bf(v);
            }
    }
}

// ---------------- bf16 MFMA GEMM, 128x64 tile, BK=32 (Wo projection) ----------------
__global__ __launch_bounds__(256) void gemm_wo(const unsigned short* __restrict__ A,
                                               const unsigned short* __restrict__ Bt,
                                               const float* __restrict__ bias,
                                               float* __restrict__ outp) {
    constexpr int K = 1024;
    __shared__ __align__(16) unsigned short As[128 * 32];   // 8 KB
    __shared__ __align__(16) unsigned short Bs[64 * 32];    // 4 KB
    const int t = threadIdx.x;
    const int w = t >> 6, l = t & 63;
    const int l15 = l & 15, lg = l >> 4;
    const int bx = blockIdx.x, by = blockIdx.y;

    f32x4 acc[2][4] = {};

    const int srow = l >> 2;
    const int sk   = (l & 3) * 8;
    const int brow = t >> 2;
    const int bk   = (t & 3) * 8;
    const unsigned short* Abase = A  + (size_t)(by * 128) * K;
    const unsigned short* Bbase = Bt + (size_t)(bx * 64) * K;

    for (int k0 = 0; k0 < K; k0 += 32) {
#pragma unroll
        for (int i = 0; i < 2; ++i) {
            const int row = w * 32 + i * 16 + srow;
            gload_lds16(Abase + (size_t)row * K + k0 + sk, &As[row * 32 + sk]);
        }
        gload_lds16(Bbase + (size_t)brow * K + k0 + bk, &Bs[brow * 32 + bk]);
        __syncthreads();

        bf16x8 af[2], bfr[4];
#pragma unroll
        for (int mi = 0; mi < 2; ++mi)
            af[mi] = *(const bf16x8*)&As[(w * 32 + mi * 16 + l15) * 32 + lg * 8];
#pragma unroll
        for (int ni = 0; ni < 4; ++ni)
            bfr[ni] = *(const bf16x8*)&Bs[(ni * 16 + l15) * 32 + lg * 8];
#pragma unroll
        for (int mi = 0; mi < 2; ++mi)
#pragma unroll
            for (int ni = 0; ni < 4; ++ni)
                acc[mi][ni] = __builtin_amdgcn_mfma_f32_16x16x32_bf16(af[mi], bfr[ni], acc[mi][ni], 0, 0, 0);
        __syncthreads();
    }

#pragma unroll
    for (int ni = 0; ni < 4; ++ni) {
        const int n = bx * 64 + ni * 16 + l15;
        const float bv = bias[n];
#pragma unroll
        for (int mi = 0; mi < 2; ++mi)
#pragma unroll
            for (int i = 0; i < 4; ++i) {
                const int m = by * 128 + w * 32 + mi * 16 + lg * 4 + i;
                outp[(size_t)m * DM + n] = acc[mi][ni][i] + bv;
            }
    }
}

// ---------------- 32x32-MFMA causal flash attention, V-in-register pipeline ----------------
// Q (pre-scaled, exp2 domain), K: bf16 [B,H,S,DK]; Vt: bf16 [B,H,DK,S]; O: bf16 [B,S,DM].
// Grid 2048 = 64 q-tiles x 32 bh; qi = 63-(bid>>5) (LPT). Block = 2 waves; wave w does
// kv tiles kt%2==w. K staged via gload_lds into PRIVATE 8KB buffer (rotated prefetch);
// V loaded DIRECTLY to registers at loop top (lane's fragment rows are static in global).
__global__ __launch_bounds__(128) void attn32(const unsigned short* __restrict__ Qg,
                                              const unsigned short* __restrict__ Kg,
                                              const unsigned short* __restrict__ Vtg,
                                              unsigned short* __restrict__ O) {
    __shared__ __align__(16) char Ks[2][8192];   // per-wave K tile (dead after QK^T -> merge region)
    __shared__ float mml[2][64][2];              // per-wave (m, l) partials
    const float NEG_INF = -__builtin_inff();

    const int bid = blockIdx.x;
    const int bh  = bid & 31;          // mod-256 striping: CU's blocks share bh (L2-local K/V)
    const int qi  = 63 - (bid >> 5);   // 32-row q-tile, big tiles dispatched first
    const int b = bh >> 4, h = bh & 15;
    const size_t base = (size_t)bh * SQ * DK;

    const int t = threadIdx.x;         // 0..127
    const int w = t >> 6, l = t & 63;  // wave w owns kv tiles kt%2==w
    const int l31 = l & 31, hi = l >> 5;
    const bool h0 = (hi == 0);
    const int xl = l31;

    char* Ks0 = Ks[w];
    float* myP = (float*)Ks[w];        // merge region (K buffer dead by then)
    float* otP = (float*)Ks[w ^ 1];

    // K staging: lane covers LDS row (i*8 + l>>3), 16B slot (l&7); pre-swizzled source chunk
    const int lrow = l >> 3;
    const int lchunk = (l & 7) ^ lrow;
    const unsigned short* ksrc0 = Kg + base + (size_t)lrow * DK + lchunk * 8;
    // V direct: lane's fragments are rows l31 and 32+l31 of Vt, cols hi*8 + 16*vi
    const unsigned short* vsrc_r0 = Vtg + (size_t)(bh * 64 + l31) * SQ + hi * 8;
    const unsigned short* vsrc_r1 = Vtg + (size_t)(bh * 64 + 32 + l31) * SQ + hi * 8;

    // swizzled K read byte-offsets for chunk c: slot = (hi + 2c) ^ (row&7)
    int roff[4];
#pragma unroll
    for (int c = 0; c < 4; ++c) roff[c] = (hi * 16 + 32 * c) ^ ((l & 7) << 4);
    const int rb0 = l31 * 128, rb1 = (32 + l31) * 128;

    const int T    = (qi >> 1) + 1;           // 64-key kv tiles for this q-tile
    const int qrow = qi * 32 + l31;

    // Q B-fragments (pre-scaled): lane holds Q[q=l31][hi*8 + 16c + j]
    bf16x8 qf[4];
    {
        const unsigned short* qp = Qg + base + (size_t)qrow * DK + hi * 8;
#pragma unroll
        for (int c = 0; c < 4; ++c) qf[c] = *(const bf16x8*)(qp + 16 * c);
    }

    float mrun = NEG_INF, lsum = 0.f;
    f32x16 o0 = {}, o1 = {};

    // prologue: issue first K tile (guarded: wave 1 may have no tiles when T==1)
    if (w < T) {
        const unsigned short* ks = ksrc0 + (size_t)w * 64 * DK;
#pragma unroll
        for (int j = 0; j < 8; ++j)
            gload_lds16(ks + j * 8 * DK, (unsigned short*)Ks0 + j * 512 + l * 8);
    }

#pragma unroll 1
    for (int kt = w; kt < T; kt += 2) {
        // ---- V fragments: direct global->register loads (issued early, used at PV) ----
        bf16x8 va[8];
        {
            const unsigned short* v0 = vsrc_r0 + kt * 64;
            const unsigned short* v1 = vsrc_r1 + kt * 64;
#pragma unroll
            for (int vi = 0; vi < 4; ++vi) {
                va[vi]     = *(const bf16x8*)(v0 + 16 * vi);
                va[4 + vi] = *(const bf16x8*)(v1 + 16 * vi);
            }
        }
        // wait K(kt) done (V register loads remain in flight; compiler waits before PV use)
        asm volatile("s_waitcnt vmcnt(8)" ::: "memory");

        // ---- S^T = K Q^T (exp2-domain scores) ----
        f32x16 s0v = {}, s1v = {};
#pragma unroll
        for (int c = 0; c < 4; ++c) {
            bf16x8 ka0 = *(const bf16x8*)(Ks0 + rb0 + roff[c]);
            bf16x8 ka1 = *(const bf16x8*)(Ks0 + rb1 + roff[c]);
            s0v = __builtin_amdgcn_mfma_f32_32x32x16_bf16(ka0, qf[c], s0v, 0, 0, 0);
            s1v = __builtin_amdgcn_mfma_f32_32x32x16_bf16(ka1, qf[c], s1v, 0, 0, 0);
        }

        float s[32];
#pragma unroll
        for (int r = 0; r < 16; ++r) { s[r] = s0v[r]; s[16 + r] = s1v[r]; }
        if (kt == T - 1) {   // causal mask, diagonal tile only
            const int qrel = qrow - kt * 64;
#pragma unroll
            for (int r = 0; r < 16; ++r) {
                const int key0 = (r & 3) + 8 * (r >> 2) + 4 * hi;   // verified C/D row map
                if (key0 > qrel) s[r] = NEG_INF;
                if (key0 + 32 > qrel) s[16 + r] = NEG_INF;
            }
        }

        // ---- tree max ----
        float t8[8];
#pragma unroll
        for (int j = 0; j < 8; ++j)
            t8[j] = fmaxf(fmaxf(s[j], s[j + 8]), fmaxf(s[j + 16], s[j + 24]));
        float tm = fmaxf(fmaxf(fmaxf(t8[0], t8[1]), fmaxf(t8[2], t8[3])),
                         fmaxf(fmaxf(t8[4], t8[5]), fmaxf(t8[6], t8[7])));
        tm = fmaxf(tm, sx32f(tm));   // lane-partner holds other 32 keys

        // ---- defer-max: skip O-rescale while growth <= 11 (log2 domain) ----
        const float mn = fmaxf(mrun, tm);
        if (!__all(tm - mrun <= 11.0f)) {     // first active tile always rescales
            const float corr = exp2v(mrun - mn);
            lsum *= corr;
#pragma unroll
            for (int r = 0; r < 16; ++r) { o0[r] *= corr; o1[r] *= corr; }
            mrun = mn;
        }

#pragma unroll
        for (int r = 0; r < 32; ++r) s[r] = exp2v(s[r] - mrun);   // masked -> 0
        float a8[8];
#pragma unroll
        for (int j = 0; j < 8; ++j)
            a8[j] = (s[j] + s[j + 8]) + (s[j + 16] + s[j + 24]);
        lsum += ((a8[0] + a8[1]) + (a8[2] + a8[3])) + ((a8[4] + a8[5]) + (a8[6] + a8[7]));

        // ---- rotate K-stage: Ks0 dead after QK^T ds_reads -> issue K(kt+2) now ----
        const bool more = (kt + 2 < T);
        if (more) {
            const unsigned short* ks = ksrc0 + (size_t)(kt + 2) * 64 * DK;
#pragma unroll
            for (int j = 0; j < 8; ++j)
                gload_lds16(ks + j * 8 * DK, (unsigned short*)Ks0 + j * 512 + l * 8);
        }

        // ---- P -> bf16 packs + lane-partner exchange -> PV B-fragments ----
        uint32_t pk[16];
#pragma unroll
        for (int j = 0; j < 16; ++j) pk[j] = cvtpk(s[2 * j], s[2 * j + 1]);
        const uint32_t X1 = sx32(h0 ? pk[2]  : pk[0]);
        const uint32_t X2 = sx32(h0 ? pk[3]  : pk[1]);
        const uint32_t X3 = sx32(h0 ? pk[6]  : pk[4]);
        const uint32_t X4 = sx32(h0 ? pk[7]  : pk[5]);
        const uint32_t X5 = sx32(h0 ? pk[10] : pk[8]);
        const uint32_t X6 = sx32(h0 ? pk[11] : pk[9]);
        const uint32_t X7 = sx32(h0 ? pk[14] : pk[12]);
        const uint32_t X8 = sx32(h0 ? pk[15] : pk[13]);
        bf16x8 pf[4];
        pf[0] = mkfrag(h0 ? pk[0]  : X1, h0 ? pk[1]  : X2, h0 ? X1 : pk[2],  h0 ? X2 : pk[3]);
        pf[1] = mkfrag(h0 ? pk[4]  : X3, h0 ? pk[5]  : X4, h0 ? X3 : pk[6],  h0 ? X4 : pk[7]);
        pf[2] = mkfrag(h0 ? pk[8]  : X5, h0 ? pk[9]  : X6, h0 ? X5 : pk[10], h0 ? X6 : pk[11]);
        pf[3] = mkfrag(h0 ? pk[12] : X7, h0 ? pk[13] : X8, h0 ? X7 : pk[14], h0 ? X8 : pk[15]);

        // ---- O^T += Vt P (V fragments already in registers; compiler inserts the waitcnt) ----
#pragma unroll
        for (int vi = 0; vi < 4; ++vi) {
            o0 = __builtin_amdgcn_mfma_f32_32x32x16_bf16(va[vi],     pf[vi], o0, 0, 0, 0);
            o1 = __builtin_amdgcn_mfma_f32_32x32x16_bf16(va[4 + vi], pf[vi], o1, 0, 0, 0);
        }
    }

    // ---- in-block merge of the two waves' partials (LSE merge, XOR layout in dead K buffer) ----
    lsum += sx32f(lsum);   // combine lane-partner key-halves first
    {
        float* pb = myP;
#pragma unroll
        for (int r = 0; r < 16; ++r) {
            pb[l * 32 + (r ^ xl)] = o0[r];
            pb[l * 32 + ((16 + r) ^ xl)] = o1[r];
        }
        mml[w][l][0] = mrun; mml[w][l][1] = lsum;
    }
    __syncthreads();   // cross-wave: partials visible
    {
        const float* qb = otP;
        const float pm = mml[w ^ 1][l][0], pl = mml[w ^ 1][l][1];
        const float mm = fmaxf(mrun, pm);
        const float ca = exp2v(mrun - mm);   // exp2(-inf)=0 handles empty partials
        const float cb = exp2v(pm - mm);
        const float lm = lsum * ca + pl * cb;
        if (w == 0) {   // wave 0 writes the merged result
            const float inv = 1.f / lm;
            unsigned short* op = O + ((size_t)(b * SQ + qrow)) * DM + h * 64;
#pragma unroll
            for (int r = 0; r < 16; r += 2) {
                const int d = (r & 3) + 8 * (r >> 2) + 4 * hi;   // d even; d+1 = next reg
                const float e0 = o0[r] * ca + qb[l * 32 + (r ^ xl)] * cb;
                const float e1 = o0[r + 1] * ca + qb[l * 32 + ((r + 1) ^ xl)] * cb;
                const float f0 = o1[r] * ca + qb[l * 32 + ((16 + r) ^ xl)] * cb;
                const float f1 = o1[r + 1] * ca + qb[l * 32 + ((16 + r + 1) ^ xl)] * cb;
                uint32_t w0 = (uint32_t)f2bf(e0 * inv) | ((uint32_t)f2bf(e1 * inv) << 16);
                uint32_t w1 = (uint32_t)f2bf(f0 * inv) | ((uint32_t)f2bf(f1 * inv) << 16);
                *(uint32_t*)(op + d) = w0;
                *(uint32_t*)(op + 32 + d) = w1;
            }
        }
    }
}

extern "C" void kernel_launch(void* const* d_in, const int* in_sizes, int n_in,
                              void* d_out, int out_size, void* d_ws, size_t ws_size,
                              hipStream_t stream) {
    const float* x  = (const float*)d_in[0];
    const float* Wq = (const float*)d_in[1];
    const float* bq = (const float*)d_in[2];
    const float* Wk = (const float*)d_in[3];
    const float* bk = (const float*)d_in[4];
    const float* Wv = (const float*)d_in[5];
    const float* bv = (const float*)d_in[6];
    const float* Wo = (const float*)d_in[7];
    const float* bo = (const float*)d_in[8];
    float* out = (float*)d_out;

    char* ws = (char*)d_ws;
    const size_t XB_BYTES = (size_t)M * DM * 2;        // 8 MB
    const size_t W_BYTES  = (size_t)DM * DM * 2;       // 2 MB
    const size_t H_BYTES  = (size_t)NB * NH * SQ * DK * 2; // 8 MB
    unsigned short* xb  = (unsigned short*)ws;                         // x bf16; later aliased as O
    unsigned short* wqt = (unsigned short*)(ws + XB_BYTES);            // wqt/wkt/wvt/wot contiguous
    unsigned short* wot = (unsigned short*)(ws + XB_BYTES + 3 * W_BYTES);
    unsigned short* Qb  = (unsigned short*)(ws + XB_BYTES + 4 * W_BYTES);
    unsigned short* Kb  = (unsigned short*)(ws + XB_BYTES + 4 * W_BYTES + H_BYTES);
    unsigned short* Vb  = (unsigned short*)(ws + XB_BYTES + 4 * W_BYTES + 2 * H_BYTES); // [B,H,DK,S]

    // merged setup: x-convert (2048 blocks) + 4x W transpose-convert (4096 blocks)
    cvt_all<<<6144, 256, 0, stream>>>(x, xb, Wq, Wk, Wv, Wo, wqt);

    // fused QKV projection: N = 3072, grid 24x32 = 768 blocks = 3/CU
    gemm128<<<dim3(24, 32), 256, 0, stream>>>(xb, wqt, bq, bk, bv, Qb);

    attn32<<<NB * NH * 64, 128, 0, stream>>>(Qb, Kb, Vb, xb /* O aliases xb */);

    // output projection: N = 1024, BN=64 -> 512 blocks = 2/CU
    gemm_wo<<<dim3(16, 32), 256, 0, stream>>>(xb, wot, bo, out);
}

// Round 29
// 116.900 us; speedup vs baseline: 1.0294x; 1.0294x over previous
//
// r29 == r27 (best: 117.36 us): rotated K-stage attn + gemm128 QKV + gemm_wo + merged cvt.
#include <hip/hip_runtime.h>
#include <stdint.h>

typedef __attribute__((ext_vector_type(8))) short bf16x8;
typedef __attribute__((ext_vector_type(8))) unsigned short ushort8;
typedef __attribute__((ext_vector_type(4))) float f32x4;
typedef __attribute__((ext_vector_type(16))) float f32x16;

constexpr int DM = 1024;   // d_model
constexpr int SQ = 2048;   // seq len
constexpr int NB = 2;      // batch
constexpr int NH = 16;     // heads
constexpr int DK = 64;     // head dim
constexpr int M  = NB * SQ; // 4096 rows

__device__ inline float bf2f(unsigned short u) {
    union { uint32_t i; float f; } c; c.i = ((uint32_t)u) << 16; return c.f;
}
__device__ inline unsigned short f2bf(float f) {
    union { float f; uint32_t i; } c; c.f = f;
    uint32_t r = c.i + 0x7FFFu + ((c.i >> 16) & 1u);   // round-to-nearest-even
    return (unsigned short)(r >> 16);
}
__device__ inline float exp2v(float x) {    // v_exp_f32: D = 2^S0
    float r;
    asm("v_exp_f32 %0, %1" : "=v"(r) : "v"(x));
    return r;
}
__device__ inline uint32_t cvtpk(float lo, float hi) {
    uint32_t r;
    asm("v_cvt_pk_bf16_f32 %0, %1, %2" : "=v"(r) : "v"(lo), "v"(hi));
    return r;
}
__device__ inline uint32_t sx32(uint32_t v) {   // exchange with partner lane (l ^ 32)
    return (uint32_t)__shfl_xor((int)v, 32);
}
__device__ inline float sx32f(float v) {
    return __shfl_xor(v, 32);
}
__device__ inline bf16x8 mkfrag(uint32_t a, uint32_t b, uint32_t c, uint32_t d) {
    union { bf16x8 v; uint32_t u[4]; } m;
    m.u[0] = a; m.u[1] = b; m.u[2] = c; m.u[3] = d;
    return m.v;
}
__device__ inline void gload_lds16(const unsigned short* g, unsigned short* l) {
    __builtin_amdgcn_global_load_lds(
        (const __attribute__((address_space(1))) void*)g,
        (__attribute__((address_space(3))) void*)l, 16, 0, 0);
}

// ------- merged setup: x fp32->bf16 (bids 0..2047) + 4x W transpose-convert (bids 2048..6143) -------
__global__ __launch_bounds__(256) void cvt_all(const float* __restrict__ x,
                                               unsigned short* __restrict__ xb,
                                               const float* __restrict__ W0,
                                               const float* __restrict__ W1,
                                               const float* __restrict__ W2,
                                               const float* __restrict__ W3,
                                               unsigned short* __restrict__ WtBase) {
    __shared__ float tile[32][33];
    const int bid = blockIdx.x;
    const int t = threadIdx.x;
    if (bid < 2048) {   // --- cvt_x part ---
        int idx = (bid * 256 + t) * 8;
        const float* p = x + idx;
        ushort8 o;
#pragma unroll
        for (int i = 0; i < 8; ++i) o[i] = f2bf(p[i]);
        *(ushort8*)(xb + idx) = o;
        return;
    }
    // --- cvt_w part ---
    const int wid = bid - 2048;          // 0..4095
    const int z = wid >> 10;             // matrix 0..3
    const int rem = wid & 1023;
    const int bx = rem & 31, by = rem >> 5;
    const float* W = (z == 0) ? W0 : (z == 1) ? W1 : (z == 2) ? W2 : W3;
    unsigned short* Wt = WtBase + (size_t)z * DM * DM;
    const int tx = t & 31, ty = t >> 5;  // 32 x 8 (same mapping as the old (32,8) block)
#pragma unroll
    for (int j = 0; j < 4; ++j)
        tile[ty + j * 8][tx] = W[(size_t)(by * 32 + ty + j * 8) * DM + bx * 32 + tx];
    __syncthreads();
#pragma unroll
    for (int j = 0; j < 4; ++j)
        Wt[(size_t)(bx * 32 + ty + j * 8) * DM + by * 32 + tx] = f2bf(tile[tx][ty + j * 8]);
}

// ---------------- bf16 MFMA GEMM, 128x128 tile, BK=32 (QKV projection, r20) ----------------
// Fused QKV. Q written PRE-SCALED by 0.125*log2e; Q,K [B,H,S,DK]; V^T [B,H,DK,S].
__global__ __launch_bounds__(256) void gemm128(const unsigned short* __restrict__ A,
                                               const unsigned short* __restrict__ Bt,
                                               const float* __restrict__ b0,
                                               const float* __restrict__ b1,
                                               const float* __restrict__ b2,
                                               unsigned short* __restrict__ outp) {
    constexpr int K = 1024;
    __shared__ __align__(16) unsigned short As[128 * 32];
    __shared__ __align__(16) unsigned short Bs[128 * 32];
    const int t = threadIdx.x;
    const int w = t >> 6, l = t & 63;
    const int l15 = l & 15, lg = l >> 4;
    const int wr = w >> 1, wc = w & 1;
    const int bx = blockIdx.x, by = blockIdx.y;

    f32x4 acc[4][4] = {};

    const int srow = l >> 2;
    const int sk   = (l & 3) * 8;
    const unsigned short* Abase = A  + (size_t)(by * 128) * K;
    const unsigned short* Bbase = Bt + (size_t)(bx * 128) * K;

    for (int k0 = 0; k0 < K; k0 += 32) {
#pragma unroll
        for (int i = 0; i < 2; ++i) {
            const int row = w * 32 + i * 16 + srow;
            gload_lds16(Abase + (size_t)row * K + k0 + sk, &As[row * 32 + sk]);
            gload_lds16(Bbase + (size_t)row * K + k0 + sk, &Bs[row * 32 + sk]);
        }
        __syncthreads();

        bf16x8 af[4], bfr[4];
#pragma unroll
        for (int mi = 0; mi < 4; ++mi)
            af[mi] = *(const bf16x8*)&As[(wr * 64 + mi * 16 + l15) * 32 + lg * 8];
#pragma unroll
        for (int ni = 0; ni < 4; ++ni)
            bfr[ni] = *(const bf16x8*)&Bs[(wc * 64 + ni * 16 + l15) * 32 + lg * 8];
#pragma unroll
        for (int mi = 0; mi < 4; ++mi)
#pragma unroll
            for (int ni = 0; ni < 4; ++ni)
                acc[mi][ni] = __builtin_amdgcn_mfma_f32_16x16x32_bf16(af[mi], bfr[ni], acc[mi][ni], 0, 0, 0);
        __syncthreads();
    }

#pragma unroll
    for (int ni = 0; ni < 4; ++ni) {
        const int n = bx * 128 + wc * 64 + ni * 16 + l15;
        const int mat = n >> 10;   // wave-uniform (128-tile never spans matrices)
        const float* bp = (mat == 0) ? b0 : (mat == 1) ? b1 : b2;
        const float bias = bp[n & 1023];
#pragma unroll
        for (int mi = 0; mi < 4; ++mi)
#pragma unroll
            for (int i = 0; i < 4; ++i) {
                const int m = by * 128 + wr * 64 + mi * 16 + lg * 4 + i;
                float v = acc[mi][ni][i] + bias;
                const int c = n & 1023;
                if (mat == 0) v *= 0.18033688f;   // 0.125 * log2(e): scores in exp2 domain
                const int h = c >> 6, d = c & 63;
                const int b = m >> 11, si = m & 2047;
                size_t idx;
                if (mat == 2)   // V transposed: [B,H,DK,S]
                    idx = ((size_t)(b * NH + h) * DK + d) * SQ + si;
                else
                    idx = ((size_t)(b * NH + h) * SQ + si) * DK + d;
                outp[(size_t)mat * (NB * NH * SQ * DK) + idx] = f2bf(v);
            }
    }
}

// ---------------- bf16 MFMA GEMM, 128x64 tile, BK=32 (Wo projection) ----------------
__global__ __launch_bounds__(256) void gemm_wo(const unsigned short* __restrict__ A,
                                               const unsigned short* __restrict__ Bt,
                                               const float* __restrict__ bias,
                                               float* __restrict__ outp) {
    constexpr int K = 1024;
    __shared__ __align__(16) unsigned short As[128 * 32];   // 8 KB
    __shared__ __align__(16) unsigned short Bs[64 * 32];    // 4 KB
    const int t = threadIdx.x;
    const int w = t >> 6, l = t & 63;
    const int l15 = l & 15, lg = l >> 4;
    const int bx = blockIdx.x, by = blockIdx.y;

    f32x4 acc[2][4] = {};

    const int srow = l >> 2;
    const int sk   = (l & 3) * 8;
    const int brow = t >> 2;
    const int bk   = (t & 3) * 8;
    const unsigned short* Abase = A  + (size_t)(by * 128) * K;
    const unsigned short* Bbase = Bt + (size_t)(bx * 64) * K;

    for (int k0 = 0; k0 < K; k0 += 32) {
#pragma unroll
        for (int i = 0; i < 2; ++i) {
            const int row = w * 32 + i * 16 + srow;
            gload_lds16(Abase + (size_t)row * K + k0 + sk, &As[row * 32 + sk]);
        }
        gload_lds16(Bbase + (size_t)brow * K + k0 + bk, &Bs[brow * 32 + bk]);
        __syncthreads();

        bf16x8 af[2], bfr[4];
#pragma unroll
        for (int mi = 0; mi < 2; ++mi)
            af[mi] = *(const bf16x8*)&As[(w * 32 + mi * 16 + l15) * 32 + lg * 8];
#pragma unroll
        for (int ni = 0; ni < 4; ++ni)
            bfr[ni] = *(const bf16x8*)&Bs[(ni * 16 + l15) * 32 + lg * 8];
#pragma unroll
        for (int mi = 0; mi < 2; ++mi)
#pragma unroll
            for (int ni = 0; ni < 4; ++ni)
                acc[mi][ni] = __builtin_amdgcn_mfma_f32_16x16x32_bf16(af[mi], bfr[ni], acc[mi][ni], 0, 0, 0);
        __syncthreads();
    }

#pragma unroll
    for (int ni = 0; ni < 4; ++ni) {
        const int n = bx * 64 + ni * 16 + l15;
        const float bv = bias[n];
#pragma unroll
        for (int mi = 0; mi < 2; ++mi)
#pragma unroll
            for (int i = 0; i < 4; ++i) {
                const int m = by * 128 + w * 32 + mi * 16 + lg * 4 + i;
                outp[(size_t)m * DM + n] = acc[mi][ni][i] + bv;
            }
    }
}

// ---------------- 32x32-MFMA causal flash attention, rotated K-stage pipeline ----------------
// Q (pre-scaled, exp2 domain), K: bf16 [B,H,S,DK]; Vt: bf16 [B,H,DK,S]; O: bf16 [B,S,DM].
// Grid 2048 = 64 q-tiles x 32 bh; qi = 63-(bid>>5) (LPT). Block = 2 waves; wave w does
// kv tiles kt%2==w into its PRIVATE 16KB buffer. Pipeline: K(next) issued during softmax
// (Ks0 dead after QK^T ds_reads); counted vmcnt keeps 8 loads in flight across phases.
__global__ __launch_bounds__(128) void attn32(const unsigned short* __restrict__ Qg,
                                              const unsigned short* __restrict__ Kg,
                                              const unsigned short* __restrict__ Vtg,
                                              unsigned short* __restrict__ O) {
    __shared__ __align__(16) char KV[2][16384];   // per-wave: [0,8K)=K tile, [8K,16K)=V tile
    const float NEG_INF = -__builtin_inff();

    const int bid = blockIdx.x;
    const int bh  = bid & 31;          // mod-256 striping: CU's blocks share bh (L2-local K/V)
    const int qi  = 63 - (bid >> 5);   // 32-row q-tile, big tiles dispatched first
    const int b = bh >> 4, h = bh & 15;
    const size_t base = (size_t)bh * SQ * DK;

    const int t = threadIdx.x;         // 0..127
    const int w = t >> 6, l = t & 63;  // wave w owns kv tiles kt%2==w
    const int l31 = l & 31, hi = l >> 5;
    const bool h0 = (hi == 0);

    char* Ks0 = KV[w];
    char* Vs0 = KV[w] + 8192;
    float* myP = (float*)KV[w];        // partial-merge region (reused after compute)
    float* otP = (float*)KV[w ^ 1];

    // staging: lane covers LDS row (i*8 + l>>3), 16B slot (l&7); pre-swizzled source chunk
    const int lrow = l >> 3;
    const int lchunk = (l & 7) ^ lrow;
    const unsigned short* ksrc0 = Kg + base + (size_t)lrow * DK + lchunk * 8;
    const unsigned short* vsrc0 = Vtg + (size_t)(bh * 64 + lrow) * SQ + lchunk * 8;

    // swizzled read byte-offsets for chunk c: slot = (hi + 2c) ^ (row&7)
    int roff[4];
#pragma unroll
    for (int c = 0; c < 4; ++c) roff[c] = (hi * 16 + 32 * c) ^ ((l & 7) << 4);
    const int rb0 = l31 * 128, rb1 = (32 + l31) * 128;

    const int T    = (qi >> 1) + 1;           // 64-key kv tiles for this q-tile
    const int qrow = qi * 32 + l31;

    // Q B-fragments (pre-scaled): lane holds Q[q=l31][hi*8 + 16c + j]
    bf16x8 qf[4];
    {
        const unsigned short* qp = Qg + base + (size_t)qrow * DK + hi * 8;
#pragma unroll
        for (int c = 0; c < 4; ++c) qf[c] = *(const bf16x8*)(qp + 16 * c);
    }

    float mrun = NEG_INF, lsum = 0.f;
    f32x16 o0 = {}, o1 = {};

    // prologue: issue first K tile (guarded: wave 1 may have no tiles when T==1)
    if (w < T) {
        const unsigned short* ks = ksrc0 + (size_t)w * 64 * DK;
#pragma unroll
        for (int j = 0; j < 8; ++j)
            gload_lds16(ks + j * 8 * DK, (unsigned short*)Ks0 + j * 512 + l * 8);
    }

#pragma unroll 1
    for (int kt = w; kt < T; kt += 2) {
        {   // issue V(kt): outstanding = {K(kt) 8, V(kt) 8}
            const unsigned short* vs = vsrc0 + kt * 64;
#pragma unroll
            for (int j = 0; j < 8; ++j)
                gload_lds16(vs + (size_t)j * 8 * SQ, (unsigned short*)Vs0 + j * 512 + l * 8);
        }
        // wait K(kt) done; V(kt) stays in flight under QK^T+softmax
        asm volatile("s_waitcnt vmcnt(8)" ::: "memory");

        // ---- S^T = K Q^T (exp2-domain scores) ----
        f32x16 s0v = {}, s1v = {};
#pragma unroll
        for (int c = 0; c < 4; ++c) {
            bf16x8 ka0 = *(const bf16x8*)(Ks0 + rb0 + roff[c]);
            bf16x8 ka1 = *(const bf16x8*)(Ks0 + rb1 + roff[c]);
            s0v = __builtin_amdgcn_mfma_f32_32x32x16_bf16(ka0, qf[c], s0v, 0, 0, 0);
            s1v = __builtin_amdgcn_mfma_f32_32x32x16_bf16(ka1, qf[c], s1v, 0, 0, 0);
        }

        float s[32];
#pragma unroll
        for (int r = 0; r < 16; ++r) { s[r] = s0v[r]; s[16 + r] = s1v[r]; }
        if (kt == T - 1) {   // causal mask, diagonal tile only
            const int qrel = qrow - kt * 64;
#pragma unroll
            for (int r = 0; r < 16; ++r) {
                const int key0 = (r & 3) + 8 * (r >> 2) + 4 * hi;   // verified C/D row map
                if (key0 > qrel) s[r] = NEG_INF;
                if (key0 + 32 > qrel) s[16 + r] = NEG_INF;
            }
        }

        // ---- tree max ----
        float t8[8];
#pragma unroll
        for (int j = 0; j < 8; ++j)
            t8[j] = fmaxf(fmaxf(s[j], s[j + 8]), fmaxf(s[j + 16], s[j + 24]));
        float tm = fmaxf(fmaxf(fmaxf(t8[0], t8[1]), fmaxf(t8[2], t8[3])),
                         fmaxf(fmaxf(t8[4], t8[5]), fmaxf(t8[6], t8[7])));
        tm = fmaxf(tm, sx32f(tm));   // lane-partner holds other 32 keys

        // ---- defer-max: skip O-rescale while growth <= 11 (log2 domain) ----
        const float mn = fmaxf(mrun, tm);
        if (!__all(tm - mrun <= 11.0f)) {     // first active tile always rescales
            const float corr = exp2v(mrun - mn);
            lsum *= corr;
#pragma unroll
            for (int r = 0; r < 16; ++r) { o0[r] *= corr; o1[r] *= corr; }
            mrun = mn;
        }

#pragma unroll
        for (int r = 0; r < 32; ++r) s[r] = exp2v(s[r] - mrun);   // masked -> 0
        float a8[8];
#pragma unroll
        for (int j = 0; j < 8; ++j)
            a8[j] = (s[j] + s[j + 8]) + (s[j + 16] + s[j + 24]);
        lsum += ((a8[0] + a8[1]) + (a8[2] + a8[3])) + ((a8[4] + a8[5]) + (a8[6] + a8[7]));

        // ---- rotate K-stage: Ks0 dead after QK^T ds_reads -> issue K(kt+2) now ----
        const bool more = (kt + 2 < T);
        if (more) {
            const unsigned short* ks = ksrc0 + (size_t)(kt + 2) * 64 * DK;
#pragma unroll
            for (int j = 0; j < 8; ++j)
                gload_lds16(ks + j * 8 * DK, (unsigned short*)Ks0 + j * 512 + l * 8);
        }

        // ---- P -> bf16 packs + lane-partner exchange -> PV B-fragments ----
        uint32_t pk[16];
#pragma unroll
        for (int j = 0; j < 16; ++j) pk[j] = cvtpk(s[2 * j], s[2 * j + 1]);
        const uint32_t X1 = sx32(h0 ? pk[2]  : pk[0]);
        const uint32_t X2 = sx32(h0 ? pk[3]  : pk[1]);
        const uint32_t X3 = sx32(h0 ? pk[6]  : pk[4]);
        const uint32_t X4 = sx32(h0 ? pk[7]  : pk[5]);
        const uint32_t X5 = sx32(h0 ? pk[10] : pk[8]);
        const uint32_t X6 = sx32(h0 ? pk[11] : pk[9]);
        const uint32_t X7 = sx32(h0 ? pk[14] : pk[12]);
        const uint32_t X8 = sx32(h0 ? pk[15] : pk[13]);
        bf16x8 pf[4];
        pf[0] = mkfrag(h0 ? pk[0]  : X1, h0 ? pk[1]  : X2, h0 ? X1 : pk[2],  h0 ? X2 : pk[3]);
        pf[1] = mkfrag(h0 ? pk[4]  : X3, h0 ? pk[5]  : X4, h0 ? X3 : pk[6],  h0 ? X4 : pk[7]);
        pf[2] = mkfrag(h0 ? pk[8]  : X5, h0 ? pk[9]  : X6, h0 ? X5 : pk[10], h0 ? X6 : pk[11]);
        pf[3] = mkfrag(h0 ? pk[12] : X7, h0 ? pk[13] : X8, h0 ? X7 : pk[14], h0 ? X8 : pk[15]);

        // wait V(kt) done; K(kt+2) stays in flight under PV + next softmax
        if (more) { asm volatile("s_waitcnt vmcnt(8)" ::: "memory"); }
        else      { asm volatile("s_waitcnt vmcnt(0)" ::: "memory"); }

        // ---- O^T += Vt P ----
#pragma unroll
        for (int vi = 0; vi < 4; ++vi) {
            bf16x8 va0 = *(const bf16x8*)(Vs0 + rb0 + roff[vi]);
            bf16x8 va1 = *(const bf16x8*)(Vs0 + rb1 + roff[vi]);
            o0 = __builtin_amdgcn_mfma_f32_32x32x16_bf16(va0, pf[vi], o0, 0, 0, 0);
            o1 = __builtin_amdgcn_mfma_f32_32x32x16_bf16(va1, pf[vi], o1, 0, 0, 0);
        }
    }

    // ---- in-block merge of the two waves' partials (LSE merge) ----
    lsum += sx32f(lsum);   // combine lane-partner key-halves first
    {
        float* pb = myP + (size_t)l * 40;   // 160B/lane stride
#pragma unroll
        for (int r = 0; r < 16; ++r) { pb[r] = o0[r]; pb[16 + r] = o1[r]; }
        pb[32] = mrun; pb[33] = lsum;
    }
    __syncthreads();   // cross-wave: partials visible (also drains any stray vmcnt)
    {
        const float* qb = otP + (size_t)l * 40;
        const float pm = qb[32], pl = qb[33];
        const float mm = fmaxf(mrun, pm);
        const float ca = exp2v(mrun - mm);   // exp2(-inf)=0 handles empty partials
        const float cb = exp2v(pm - mm);
        const float lm = lsum * ca + pl * cb;
        if (w == 0) {   // wave 0 writes the merged result
            const float inv = 1.f / lm;
            unsigned short* op = O + ((size_t)(b * SQ + qrow)) * DM + h * 64;
#pragma unroll
            for (int r = 0; r < 16; r += 2) {
                const int d = (r & 3) + 8 * (r >> 2) + 4 * hi;   // d even; d+1 = next reg
                const float e0 = o0[r] * ca + qb[r] * cb;
                const float e1 = o0[r + 1] * ca + qb[r + 1] * cb;
                const float f0 = o1[r] * ca + qb[16 + r] * cb;
                const float f1 = o1[r + 1] * ca + qb[16 + r + 1] * cb;
                uint32_t w0 = (uint32_t)f2bf(e0 * inv) | ((uint32_t)f2bf(e1 * inv) << 16);
                uint32_t w1 = (uint32_t)f2bf(f0 * inv) | ((uint32_t)f2bf(f1 * inv) << 16);
                *(uint32_t*)(op + d) = w0;
                *(uint32_t*)(op + 32 + d) = w1;
            }
        }
    }
}

extern "C" void kernel_launch(void* const* d_in, const int* in_sizes, int n_in,
                              void* d_out, int out_size, void* d_ws, size_t ws_size,
                              hipStream_t stream) {
    const float* x  = (const float*)d_in[0];
    const float* Wq = (const float*)d_in[1];
    const float* bq = (const float*)d_in[2];
    const float* Wk = (const float*)d_in[3];
    const float* bk = (const float*)d_in[4];
    const float* Wv = (const float*)d_in[5];
    const float* bv = (const float*)d_in[6];
    const float* Wo = (const float*)d_in[7];
    const float* bo = (const float*)d_in[8];
    float* out = (float*)d_out;

    char* ws = (char*)d_ws;
    const size_t XB_BYTES = (size_t)M * DM * 2;        // 8 MB
    const size_t W_BYTES  = (size_t)DM * DM * 2;       // 2 MB
    const size_t H_BYTES  = (size_t)NB * NH * SQ * DK * 2; // 8 MB
    unsigned short* xb  = (unsigned short*)ws;                         // x bf16; later aliased as O
    unsigned short* wqt = (unsigned short*)(ws + XB_BYTES);            // wqt/wkt/wvt/wot contiguous
    unsigned short* wot = (unsigned short*)(ws + XB_BYTES + 3 * W_BYTES);
    unsigned short* Qb  = (unsigned short*)(ws + XB_BYTES + 4 * W_BYTES);
    unsigned short* Kb  = (unsigned short*)(ws + XB_BYTES + 4 * W_BYTES + H_BYTES);
    unsigned short* Vb  = (unsigned short*)(ws + XB_BYTES + 4 * W_BYTES + 2 * H_BYTES); // [B,H,DK,S]

    // merged setup: x-convert (2048 blocks) + 4x W transpose-convert (4096 blocks)
    cvt_all<<<6144, 256, 0, stream>>>(x, xb, Wq, Wk, Wv, Wo, wqt);

    // fused QKV projection: N = 3072, grid 24x32 = 768 blocks = 3/CU
    gemm128<<<dim3(24, 32), 256, 0, stream>>>(xb, wqt, bq, bk, bv, Qb);

    attn32<<<NB * NH * 64, 128, 0, stream>>>(Qb, Kb, Vb, xb /* O aliases xb */);

    // output projection: N = 1024, BN=64 -> 512 blocks = 2/CU
    gemm_wo<<<dim3(16, 32), 256, 0, stream>>>(xb, wot, bo, out);
}

// Round 30
// 116.891 us; speedup vs baseline: 1.0294x; 1.0001x over previous
//
// r30 = r29 + T5 setprio around attn MFMA clusters (waves now decoupled -> m191 regime).
#include <hip/hip_runtime.h>
#include <stdint.h>

typedef __attribute__((ext_vector_type(8))) short bf16x8;
typedef __attribute__((ext_vector_type(8))) unsigned short ushort8;
typedef __attribute__((ext_vector_type(4))) float f32x4;
typedef __attribute__((ext_vector_type(16))) float f32x16;

constexpr int DM = 1024;   // d_model
constexpr int SQ = 2048;   // seq len
constexpr int NB = 2;      // batch
constexpr int NH = 16;     // heads
constexpr int DK = 64;     // head dim
constexpr int M  = NB * SQ; // 4096 rows

__device__ inline float bf2f(unsigned short u) {
    union { uint32_t i; float f; } c; c.i = ((uint32_t)u) << 16; return c.f;
}
__device__ inline unsigned short f2bf(float f) {
    union { float f; uint32_t i; } c; c.f = f;
    uint32_t r = c.i + 0x7FFFu + ((c.i >> 16) & 1u);   // round-to-nearest-even
    return (unsigned short)(r >> 16);
}
__device__ inline float exp2v(float x) {    // v_exp_f32: D = 2^S0
    float r;
    asm("v_exp_f32 %0, %1" : "=v"(r) : "v"(x));
    return r;
}
__device__ inline uint32_t cvtpk(float lo, float hi) {
    uint32_t r;
    asm("v_cvt_pk_bf16_f32 %0, %1, %2" : "=v"(r) : "v"(lo), "v"(hi));
    return r;
}
__device__ inline uint32_t sx32(uint32_t v) {   // exchange with partner lane (l ^ 32)
    return (uint32_t)__shfl_xor((int)v, 32);
}
__device__ inline float sx32f(float v) {
    return __shfl_xor(v, 32);
}
__device__ inline bf16x8 mkfrag(uint32_t a, uint32_t b, uint32_t c, uint32_t d) {
    union { bf16x8 v; uint32_t u[4]; } m;
    m.u[0] = a; m.u[1] = b; m.u[2] = c; m.u[3] = d;
    return m.v;
}
__device__ inline void gload_lds16(const unsigned short* g, unsigned short* l) {
    __builtin_amdgcn_global_load_lds(
        (const __attribute__((address_space(1))) void*)g,
        (__attribute__((address_space(3))) void*)l, 16, 0, 0);
}

// ------- merged setup: x fp32->bf16 (bids 0..2047) + 4x W transpose-convert (bids 2048..6143) -------
__global__ __launch_bounds__(256) void cvt_all(const float* __restrict__ x,
                                               unsigned short* __restrict__ xb,
                                               const float* __restrict__ W0,
                                               const float* __restrict__ W1,
                                               const float* __restrict__ W2,
                                               const float* __restrict__ W3,
                                               unsigned short* __restrict__ WtBase) {
    __shared__ float tile[32][33];
    const int bid = blockIdx.x;
    const int t = threadIdx.x;
    if (bid < 2048) {   // --- cvt_x part ---
        int idx = (bid * 256 + t) * 8;
        const float* p = x + idx;
        ushort8 o;
#pragma unroll
        for (int i = 0; i < 8; ++i) o[i] = f2bf(p[i]);
        *(ushort8*)(xb + idx) = o;
        return;
    }
    // --- cvt_w part ---
    const int wid = bid - 2048;          // 0..4095
    const int z = wid >> 10;             // matrix 0..3
    const int rem = wid & 1023;
    const int bx = rem & 31, by = rem >> 5;
    const float* W = (z == 0) ? W0 : (z == 1) ? W1 : (z == 2) ? W2 : W3;
    unsigned short* Wt = WtBase + (size_t)z * DM * DM;
    const int tx = t & 31, ty = t >> 5;  // 32 x 8 (same mapping as the old (32,8) block)
#pragma unroll
    for (int j = 0; j < 4; ++j)
        tile[ty + j * 8][tx] = W[(size_t)(by * 32 + ty + j * 8) * DM + bx * 32 + tx];
    __syncthreads();
#pragma unroll
    for (int j = 0; j < 4; ++j)
        Wt[(size_t)(bx * 32 + ty + j * 8) * DM + by * 32 + tx] = f2bf(tile[tx][ty + j * 8]);
}

// ---------------- bf16 MFMA GEMM, 128x128 tile, BK=32 (QKV projection, r20) ----------------
// Fused QKV. Q written PRE-SCALED by 0.125*log2e; Q,K [B,H,S,DK]; V^T [B,H,DK,S].
__global__ __launch_bounds__(256) void gemm128(const unsigned short* __restrict__ A,
                                               const unsigned short* __restrict__ Bt,
                                               const float* __restrict__ b0,
                                               const float* __restrict__ b1,
                                               const float* __restrict__ b2,
                                               unsigned short* __restrict__ outp) {
    constexpr int K = 1024;
    __shared__ __align__(16) unsigned short As[128 * 32];
    __shared__ __align__(16) unsigned short Bs[128 * 32];
    const int t = threadIdx.x;
    const int w = t >> 6, l = t & 63;
    const int l15 = l & 15, lg = l >> 4;
    const int wr = w >> 1, wc = w & 1;
    const int bx = blockIdx.x, by = blockIdx.y;

    f32x4 acc[4][4] = {};

    const int srow = l >> 2;
    const int sk   = (l & 3) * 8;
    const unsigned short* Abase = A  + (size_t)(by * 128) * K;
    const unsigned short* Bbase = Bt + (size_t)(bx * 128) * K;

    for (int k0 = 0; k0 < K; k0 += 32) {
#pragma unroll
        for (int i = 0; i < 2; ++i) {
            const int row = w * 32 + i * 16 + srow;
            gload_lds16(Abase + (size_t)row * K + k0 + sk, &As[row * 32 + sk]);
            gload_lds16(Bbase + (size_t)row * K + k0 + sk, &Bs[row * 32 + sk]);
        }
        __syncthreads();

        bf16x8 af[4], bfr[4];
#pragma unroll
        for (int mi = 0; mi < 4; ++mi)
            af[mi] = *(const bf16x8*)&As[(wr * 64 + mi * 16 + l15) * 32 + lg * 8];
#pragma unroll
        for (int ni = 0; ni < 4; ++ni)
            bfr[ni] = *(const bf16x8*)&Bs[(wc * 64 + ni * 16 + l15) * 32 + lg * 8];
#pragma unroll
        for (int mi = 0; mi < 4; ++mi)
#pragma unroll
            for (int ni = 0; ni < 4; ++ni)
                acc[mi][ni] = __builtin_amdgcn_mfma_f32_16x16x32_bf16(af[mi], bfr[ni], acc[mi][ni], 0, 0, 0);
        __syncthreads();
    }

#pragma unroll
    for (int ni = 0; ni < 4; ++ni) {
        const int n = bx * 128 + wc * 64 + ni * 16 + l15;
        const int mat = n >> 10;   // wave-uniform (128-tile never spans matrices)
        const float* bp = (mat == 0) ? b0 : (mat == 1) ? b1 : b2;
        const float bias = bp[n & 1023];
#pragma unroll
        for (int mi = 0; mi < 4; ++mi)
#pragma unroll
            for (int i = 0; i < 4; ++i) {
                const int m = by * 128 + wr * 64 + mi * 16 + lg * 4 + i;
                float v = acc[mi][ni][i] + bias;
                const int c = n & 1023;
                if (mat == 0) v *= 0.18033688f;   // 0.125 * log2(e): scores in exp2 domain
                const int h = c >> 6, d = c & 63;
                const int b = m >> 11, si = m & 2047;
                size_t idx;
                if (mat == 2)   // V transposed: [B,H,DK,S]
                    idx = ((size_t)(b * NH + h) * DK + d) * SQ + si;
                else
                    idx = ((size_t)(b * NH + h) * SQ + si) * DK + d;
                outp[(size_t)mat * (NB * NH * SQ * DK) + idx] = f2bf(v);
            }
    }
}

// ---------------- bf16 MFMA GEMM, 128x64 tile, BK=32 (Wo projection) ----------------
__global__ __launch_bounds__(256) void gemm_wo(const unsigned short* __restrict__ A,
                                               const unsigned short* __restrict__ Bt,
                                               const float* __restrict__ bias,
                                               float* __restrict__ outp) {
    constexpr int K = 1024;
    __shared__ __align__(16) unsigned short As[128 * 32];   // 8 KB
    __shared__ __align__(16) unsigned short Bs[64 * 32];    // 4 KB
    const int t = threadIdx.x;
    const int w = t >> 6, l = t & 63;
    const int l15 = l & 15, lg = l >> 4;
    const int bx = blockIdx.x, by = blockIdx.y;

    f32x4 acc[2][4] = {};

    const int srow = l >> 2;
    const int sk   = (l & 3) * 8;
    const int brow = t >> 2;
    const int bk   = (t & 3) * 8;
    const unsigned short* Abase = A  + (size_t)(by * 128) * K;
    const unsigned short* Bbase = Bt + (size_t)(bx * 64) * K;

    for (int k0 = 0; k0 < K; k0 += 32) {
#pragma unroll
        for (int i = 0; i < 2; ++i) {
            const int row = w * 32 + i * 16 + srow;
            gload_lds16(Abase + (size_t)row * K + k0 + sk, &As[row * 32 + sk]);
        }
        gload_lds16(Bbase + (size_t)brow * K + k0 + bk, &Bs[brow * 32 + bk]);
        __syncthreads();

        bf16x8 af[2], bfr[4];
#pragma unroll
        for (int mi = 0; mi < 2; ++mi)
            af[mi] = *(const bf16x8*)&As[(w * 32 + mi * 16 + l15) * 32 + lg * 8];
#pragma unroll
        for (int ni = 0; ni < 4; ++ni)
            bfr[ni] = *(const bf16x8*)&Bs[(ni * 16 + l15) * 32 + lg * 8];
#pragma unroll
        for (int mi = 0; mi < 2; ++mi)
#pragma unroll
            for (int ni = 0; ni < 4; ++ni)
                acc[mi][ni] = __builtin_amdgcn_mfma_f32_16x16x32_bf16(af[mi], bfr[ni], acc[mi][ni], 0, 0, 0);
        __syncthreads();
    }

#pragma unroll
    for (int ni = 0; ni < 4; ++ni) {
        const int n = bx * 64 + ni * 16 + l15;
        const float bv = bias[n];
#pragma unroll
        for (int mi = 0; mi < 2; ++mi)
#pragma unroll
            for (int i = 0; i < 4; ++i) {
                const int m = by * 128 + w * 32 + mi * 16 + lg * 4 + i;
                outp[(size_t)m * DM + n] = acc[mi][ni][i] + bv;
            }
    }
}

// ---------------- 32x32-MFMA causal flash attention, rotated K-stage pipeline + setprio ----------------
// Q (pre-scaled, exp2 domain), K: bf16 [B,H,S,DK]; Vt: bf16 [B,H,DK,S]; O: bf16 [B,S,DM].
// Grid 2048 = 64 q-tiles x 32 bh; qi = 63-(bid>>5) (LPT). Block = 2 waves; wave w does
// kv tiles kt%2==w into its PRIVATE 16KB buffer. K(next) issued during softmax; counted
// vmcnt; waves fully decoupled -> setprio(1) around MFMA clusters (m191-positive regime).
__global__ __launch_bounds__(128) void attn32(const unsigned short* __restrict__ Qg,
                                              const unsigned short* __restrict__ Kg,
                                              const unsigned short* __restrict__ Vtg,
                                              unsigned short* __restrict__ O) {
    __shared__ __align__(16) char KV[2][16384];   // per-wave: [0,8K)=K tile, [8K,16K)=V tile
    const float NEG_INF = -__builtin_inff();

    const int bid = blockIdx.x;
    const int bh  = bid & 31;          // mod-256 striping: CU's blocks share bh (L2-local K/V)
    const int qi  = 63 - (bid >> 5);   // 32-row q-tile, big tiles dispatched first
    const int b = bh >> 4, h = bh & 15;
    const size_t base = (size_t)bh * SQ * DK;

    const int t = threadIdx.x;         // 0..127
    const int w = t >> 6, l = t & 63;  // wave w owns kv tiles kt%2==w
    const int l31 = l & 31, hi = l >> 5;
    const bool h0 = (hi == 0);

    char* Ks0 = KV[w];
    char* Vs0 = KV[w] + 8192;
    float* myP = (float*)KV[w];        // partial-merge region (reused after compute)
    float* otP = (float*)KV[w ^ 1];

    // staging: lane covers LDS row (i*8 + l>>3), 16B slot (l&7); pre-swizzled source chunk
    const int lrow = l >> 3;
    const int lchunk = (l & 7) ^ lrow;
    const unsigned short* ksrc0 = Kg + base + (size_t)lrow * DK + lchunk * 8;
    const unsigned short* vsrc0 = Vtg + (size_t)(bh * 64 + lrow) * SQ + lchunk * 8;

    // swizzled read byte-offsets for chunk c: slot = (hi + 2c) ^ (row&7)
    int roff[4];
#pragma unroll
    for (int c = 0; c < 4; ++c) roff[c] = (hi * 16 + 32 * c) ^ ((l & 7) << 4);
    const int rb0 = l31 * 128, rb1 = (32 + l31) * 128;

    const int T    = (qi >> 1) + 1;           // 64-key kv tiles for this q-tile
    const int qrow = qi * 32 + l31;

    // Q B-fragments (pre-scaled): lane holds Q[q=l31][hi*8 + 16c + j]
    bf16x8 qf[4];
    {
        const unsigned short* qp = Qg + base + (size_t)qrow * DK + hi * 8;
#pragma unroll
        for (int c = 0; c < 4; ++c) qf[c] = *(const bf16x8*)(qp + 16 * c);
    }

    float mrun = NEG_INF, lsum = 0.f;
    f32x16 o0 = {}, o1 = {};

    // prologue: issue first K tile (guarded: wave 1 may have no tiles when T==1)
    if (w < T) {
        const unsigned short* ks = ksrc0 + (size_t)w * 64 * DK;
#pragma unroll
        for (int j = 0; j < 8; ++j)
            gload_lds16(ks + j * 8 * DK, (unsigned short*)Ks0 + j * 512 + l * 8);
    }

#pragma unroll 1
    for (int kt = w; kt < T; kt += 2) {
        {   // issue V(kt): outstanding = {K(kt) 8, V(kt) 8}
            const unsigned short* vs = vsrc0 + kt * 64;
#pragma unroll
            for (int j = 0; j < 8; ++j)
                gload_lds16(vs + (size_t)j * 8 * SQ, (unsigned short*)Vs0 + j * 512 + l * 8);
        }
        // wait K(kt) done; V(kt) stays in flight under QK^T+softmax
        asm volatile("s_waitcnt vmcnt(8)" ::: "memory");

        // ---- S^T = K Q^T (exp2-domain scores), boosted priority ----
        __builtin_amdgcn_s_setprio(1);
        f32x16 s0v = {}, s1v = {};
#pragma unroll
        for (int c = 0; c < 4; ++c) {
            bf16x8 ka0 = *(const bf16x8*)(Ks0 + rb0 + roff[c]);
            bf16x8 ka1 = *(const bf16x8*)(Ks0 + rb1 + roff[c]);
            s0v = __builtin_amdgcn_mfma_f32_32x32x16_bf16(ka0, qf[c], s0v, 0, 0, 0);
            s1v = __builtin_amdgcn_mfma_f32_32x32x16_bf16(ka1, qf[c], s1v, 0, 0, 0);
        }
        __builtin_amdgcn_s_setprio(0);

        float s[32];
#pragma unroll
        for (int r = 0; r < 16; ++r) { s[r] = s0v[r]; s[16 + r] = s1v[r]; }
        if (kt == T - 1) {   // causal mask, diagonal tile only
            const int qrel = qrow - kt * 64;
#pragma unroll
            for (int r = 0; r < 16; ++r) {
                const int key0 = (r & 3) + 8 * (r >> 2) + 4 * hi;   // verified C/D row map
                if (key0 > qrel) s[r] = NEG_INF;
                if (key0 + 32 > qrel) s[16 + r] = NEG_INF;
            }
        }

        // ---- tree max ----
        float t8[8];
#pragma unroll
        for (int j = 0; j < 8; ++j)
            t8[j] = fmaxf(fmaxf(s[j], s[j + 8]), fmaxf(s[j + 16], s[j + 24]));
        float tm = fmaxf(fmaxf(fmaxf(t8[0], t8[1]), fmaxf(t8[2], t8[3])),
                         fmaxf(fmaxf(t8[4], t8[5]), fmaxf(t8[6], t8[7])));
        tm = fmaxf(tm, sx32f(tm));   // lane-partner holds other 32 keys

        // ---- defer-max: skip O-rescale while growth <= 11 (log2 domain) ----
        const float mn = fmaxf(mrun, tm);
        if (!__all(tm - mrun <= 11.0f)) {     // first active tile always rescales
            const float corr = exp2v(mrun - mn);
            lsum *= corr;
#pragma unroll
            for (int r = 0; r < 16; ++r) { o0[r] *= corr; o1[r] *= corr; }
            mrun = mn;
        }

#pragma unroll
        for (int r = 0; r < 32; ++r) s[r] = exp2v(s[r] - mrun);   // masked -> 0
        float a8[8];
#pragma unroll
        for (int j = 0; j < 8; ++j)
            a8[j] = (s[j] + s[j + 8]) + (s[j + 16] + s[j + 24]);
        lsum += ((a8[0] + a8[1]) + (a8[2] + a8[3])) + ((a8[4] + a8[5]) + (a8[6] + a8[7]));

        // ---- rotate K-stage: Ks0 dead after QK^T ds_reads -> issue K(kt+2) now ----
        const bool more = (kt + 2 < T);
        if (more) {
            const unsigned short* ks = ksrc0 + (size_t)(kt + 2) * 64 * DK;
#pragma unroll
            for (int j = 0; j < 8; ++j)
                gload_lds16(ks + j * 8 * DK, (unsigned short*)Ks0 + j * 512 + l * 8);
        }

        // ---- P -> bf16 packs + lane-partner exchange -> PV B-fragments ----
        uint32_t pk[16];
#pragma unroll
        for (int j = 0; j < 16; ++j) pk[j] = cvtpk(s[2 * j], s[2 * j + 1]);
        const uint32_t X1 = sx32(h0 ? pk[2]  : pk[0]);
        const uint32_t X2 = sx32(h0 ? pk[3]  : pk[1]);
        const uint32_t X3 = sx32(h0 ? pk[6]  : pk[4]);
        const uint32_t X4 = sx32(h0 ? pk[7]  : pk[5]);
        const uint32_t X5 = sx32(h0 ? pk[10] : pk[8]);
        const uint32_t X6 = sx32(h0 ? pk[11] : pk[9]);
        const uint32_t X7 = sx32(h0 ? pk[14] : pk[12]);
        const uint32_t X8 = sx32(h0 ? pk[15] : pk[13]);
        bf16x8 pf[4];
        pf[0] = mkfrag(h0 ? pk[0]  : X1, h0 ? pk[1]  : X2, h0 ? X1 : pk[2],  h0 ? X2 : pk[3]);
        pf[1] = mkfrag(h0 ? pk[4]  : X3, h0 ? pk[5]  : X4, h0 ? X3 : pk[6],  h0 ? X4 : pk[7]);
        pf[2] = mkfrag(h0 ? pk[8]  : X5, h0 ? pk[9]  : X6, h0 ? X5 : pk[10], h0 ? X6 : pk[11]);
        pf[3] = mkfrag(h0 ? pk[12] : X7, h0 ? pk[13] : X8, h0 ? X7 : pk[14], h0 ? X8 : pk[15]);

        // wait V(kt) done; K(kt+2) stays in flight under PV + next softmax
        if (more) { asm volatile("s_waitcnt vmcnt(8)" ::: "memory"); }
        else      { asm volatile("s_waitcnt vmcnt(0)" ::: "memory"); }

        // ---- O^T += Vt P, boosted priority ----
        __builtin_amdgcn_s_setprio(1);
#pragma unroll
        for (int vi = 0; vi < 4; ++vi) {
            bf16x8 va0 = *(const bf16x8*)(Vs0 + rb0 + roff[vi]);
            bf16x8 va1 = *(const bf16x8*)(Vs0 + rb1 + roff[vi]);
            o0 = __builtin_amdgcn_mfma_f32_32x32x16_bf16(va0, pf[vi], o0, 0, 0, 0);
            o1 = __builtin_amdgcn_mfma_f32_32x32x16_bf16(va1, pf[vi], o1, 0, 0, 0);
        }
        __builtin_amdgcn_s_setprio(0);
    }

    // ---- in-block merge of the two waves' partials (LSE merge) ----
    lsum += sx32f(lsum);   // combine lane-partner key-halves first
    {
        float* pb = myP + (size_t)l * 40;   // 160B/lane stride
#pragma unroll
        for (int r = 0; r < 16; ++r) { pb[r] = o0[r]; pb[16 + r] = o1[r]; }
        pb[32] = mrun; pb[33] = lsum;
    }
    __syncthreads();   // cross-wave: partials visible (also drains any stray vmcnt)
    {
        const float* qb = otP + (size_t)l * 40;
        const float pm = qb[32], pl = qb[33];
        const float mm = fmaxf(mrun, pm);
        const float ca = exp2v(mrun - mm);   // exp2(-inf)=0 handles empty partials
        const float cb = exp2v(pm - mm);
        const float lm = lsum * ca + pl * cb;
        if (w == 0) {   // wave 0 writes the merged result
            const float inv = 1.f / lm;
            unsigned short* op = O + ((size_t)(b * SQ + qrow)) * DM + h * 64;
#pragma unroll
            for (int r = 0; r < 16; r += 2) {
                const int d = (r & 3) + 8 * (r >> 2) + 4 * hi;   // d even; d+1 = next reg
                const float e0 = o0[r] * ca + qb[r] * cb;
                const float e1 = o0[r + 1] * ca + qb[r + 1] * cb;
                const float f0 = o1[r] * ca + qb[16 + r] * cb;
                const float f1 = o1[r + 1] * ca + qb[16 + r + 1] * cb;
                uint32_t w0 = (uint32_t)f2bf(e0 * inv) | ((uint32_t)f2bf(e1 * inv) << 16);
                uint32_t w1 = (uint32_t)f2bf(f0 * inv) | ((uint32_t)f2bf(f1 * inv) << 16);
                *(uint32_t*)(op + d) = w0;
                *(uint32_t*)(op + 32 + d) = w1;
            }
        }
    }
}

extern "C" void kernel_launch(void* const* d_in, const int* in_sizes, int n_in,
                              void* d_out, int out_size, void* d_ws, size_t ws_size,
                              hipStream_t stream) {
    const float* x  = (const float*)d_in[0];
    const float* Wq = (const float*)d_in[1];
    const float* bq = (const float*)d_in[2];
    const float* Wk = (const float*)d_in[3];
    const float* bk = (const float*)d_in[4];
    const float* Wv = (const float*)d_in[5];
    const float* bv = (const float*)d_in[6];
    const float* Wo = (const float*)d_in[7];
    const float* bo = (const float*)d_in[8];
    float* out = (float*)d_out;

    char* ws = (char*)d_ws;
    const size_t XB_BYTES = (size_t)M * DM * 2;        // 8 MB
    const size_t W_BYTES  = (size_t)DM * DM * 2;       // 2 MB
    const size_t H_BYTES  = (size_t)NB * NH * SQ * DK * 2; // 8 MB
    unsigned short* xb  = (unsigned short*)ws;                         // x bf16; later aliased as O
    unsigned short* wqt = (unsigned short*)(ws + XB_BYTES);            // wqt/wkt/wvt/wot contiguous
    unsigned short* wot = (unsigned short*)(ws + XB_BYTES + 3 * W_BYTES);
    unsigned short* Qb  = (unsigned short*)(ws + XB_BYTES + 4 * W_BYTES);
    unsigned short* Kb  = (unsigned short*)(ws + XB_BYTES + 4 * W_BYTES + H_BYTES);
    unsigned short* Vb  = (unsigned short*)(ws + XB_BYTES + 4 * W_BYTES + 2 * H_BYTES); // [B,H,DK,S]

    // merged setup: x-convert (2048 blocks) + 4x W transpose-convert (4096 blocks)
    cvt_all<<<6144, 256, 0, stream>>>(x, xb, Wq, Wk, Wv, Wo, wqt);

    // fused QKV projection: N = 3072, grid 24x32 = 768 blocks = 3/CU
    gemm128<<<dim3(24, 32), 256, 0, stream>>>(xb, wqt, bq, bk, bv, Qb);

    attn32<<<NB * NH * 64, 128, 0, stream>>>(Qb, Kb, Vb, xb /* O aliases xb */);

    // output projection: N = 1024, BN=64 -> 512 blocks = 2/CU
    gemm_wo<<<dim3(16, 32), 256, 0, stream>>>(xb, wot, bo, out);
}